// Round 1
// 1887.296 us; speedup vs baseline: 1.2158x; 1.2158x over previous
//
#include <hip/hip_runtime.h>
#include <math.h>

typedef __bf16 bf16;
typedef __attribute__((ext_vector_type(8))) __bf16 bf16x8;
typedef __attribute__((ext_vector_type(4))) float f32x4;

// Model dims
static const int DM = 1024;   // D
static const int TCAT = 1280; // S + 2M
static const int NKV = 1408;  // mem(128)+hid(1024)+bK(128)+fK(128)

__device__ inline f32x4 mfma16(bf16x8 a, bf16x8 b, f32x4 c) {
  return __builtin_amdgcn_mfma_f32_16x16x32_bf16(a, b, c, 0, 0, 0);
}

// ---------------- RoPE tables (fp64 on device, matches np.float64 ref) ------
__global__ void rope_table_kernel(float* cosT, float* sinT) {
  int p = blockIdx.x, i = threadIdx.x; // 1280 x 32
  double freq = pow(10000.0, -((double)i) / 32.0);
  double a = (double)p * freq;
  cosT[p * 32 + i] = (float)cos(a);
  sinT[p * 32 + i] = (float)sin(a);
}

// ---------------- cat init: [embed[ids]; beacon; forget] --------------------
__global__ void init_cat_kernel(const int* ids, const float* embed,
                                const float* beacon, const float* forget,
                                float* cat) {
  int r = blockIdx.x, tid = threadIdx.x;
  const float* src;
  if (r < 1024) src = embed + (size_t)ids[r] * DM;
  else if (r < 1152) src = beacon + (size_t)(r - 1024) * DM;
  else src = forget + (size_t)(r - 1152) * DM;
  *(f32x4*)(cat + (size_t)r * DM + tid * 4) = *(const f32x4*)(src + tid * 4);
}

// ---------------- out[l] = mem*g + inj*(1-g), from carry at layer entry -----
__global__ void out_gate_kernel(const float* cat, const float* memL, float* outL) {
  int m = blockIdx.x, tid = threadIdx.x;
  size_t c = (size_t)tid * 4;
  f32x4 f = *(const f32x4*)(cat + (size_t)(1152 + m) * DM + c);
  f32x4 j = *(const f32x4*)(cat + (size_t)(1024 + m) * DM + c);
  f32x4 mm = *(const f32x4*)(memL + (size_t)m * DM + c);
  f32x4 o;
#pragma unroll
  for (int r = 0; r < 4; ++r) {
    float g = 1.f / (1.f + __expf(-f[r]));
    o[r] = mm[r] * g + j[r] * (1.f - g);
  }
  *(f32x4*)(outL + (size_t)m * DM + c) = o;
}

// ---------------- weight transpose + f32->bf16 ------------------------------
struct TransJob { const float* src; bf16* dst; int K; int N; int tileStart; };
struct TransArgs { TransJob j[15]; int njobs; };

__global__ __launch_bounds__(256) void trans_kernel(TransArgs args) {
  int b = blockIdx.x, ji = 0;
  while (ji + 1 < args.njobs && b >= args.j[ji + 1].tileStart) ++ji;
  TransJob J = args.j[ji];
  int t = b - J.tileStart;
  int tilesN = J.N >> 5;
  int tk = t / tilesN, tn = t - tk * tilesN;
  int k0 = tk * 32, n0 = tn * 32;
  __shared__ float tile[32][33];
  int c = threadIdx.x & 31, r0 = threadIdx.x >> 5;
#pragma unroll
  for (int i = 0; i < 4; ++i) {
    int r = r0 + i * 8;
    tile[r][c] = J.src[(size_t)(k0 + r) * J.N + n0 + c];
  }
  __syncthreads();
#pragma unroll
  for (int i = 0; i < 4; ++i) {
    int r = r0 + i * 8;
    J.dst[(size_t)(n0 + r) * J.K + k0 + c] = (bf16)tile[c][r];
  }
}

// ---------------- rmsnorm (fp32) -> bf16; tail rows = raw memory convert ----
__global__ __launch_bounds__(256) void rmsnorm_kernel(const float* x, const float* w,
                                                      bf16* out, const float* mem,
                                                      int nNorm) {
  int r = blockIdx.x, tid = threadIdx.x;
  if (r < nNorm) {
    f32x4 v = *(const f32x4*)(x + (size_t)r * DM + tid * 4);
    float ss = v[0] * v[0] + v[1] * v[1] + v[2] * v[2] + v[3] * v[3];
#pragma unroll
    for (int d = 1; d < 64; d <<= 1) ss += __shfl_xor(ss, d, 64);
    __shared__ float red[4];
    if ((tid & 63) == 0) red[tid >> 6] = ss;
    __syncthreads();
    float tot = red[0] + red[1] + red[2] + red[3];
    float scale = rsqrtf(tot * (1.0f / 1024.0f) + 1e-5f);
    f32x4 wv = *(const f32x4*)(w + tid * 4);
    bf16* o = out + (size_t)r * DM + tid * 4;
#pragma unroll
    for (int q = 0; q < 4; ++q) o[q] = (bf16)(v[q] * wv[q] * scale);
  } else {
    f32x4 v = *(const f32x4*)(mem + (size_t)(r - nNorm) * DM + tid * 4);
    bf16* o = out + (size_t)r * DM + tid * 4;
#pragma unroll
    for (int q = 0; q < 4; ++q) o[q] = (bf16)v[q];
  }
}

// ---------------- grouped bf16 GEMM: C(f32, MxN) = A(MxK) @ Bt(NxK)^T -------
// v2: 64x128 tiles, global_load_lds(16B) direct staging, LDS double-buffer,
//     depth-2 prefetch with counted vmcnt (T3+T4 minimum from the guide).
struct GemmJob { const bf16* A; const bf16* B; float* C; int K; int N; int tileStart; int addFlag; };
struct GemmArgs { GemmJob j[12]; int njobs; };

__device__ __forceinline__ void gll16(const bf16* g, bf16* l) {
  __builtin_amdgcn_global_load_lds(
      (const __attribute__((address_space(1))) void*)g,
      (__attribute__((address_space(3))) void*)l, 16, 0, 0);
}

__global__ __launch_bounds__(256, 2) void gemm_kernel(GemmArgs args) {
  int b = blockIdx.x, ji = 0;
  while (ji + 1 < args.njobs && b >= args.j[ji + 1].tileStart) ++ji;
  GemmJob J = args.j[ji];
  int t = b - J.tileStart;
  int tilesN = J.N >> 7;
  int tm = t / tilesN, tn = t - tm * tilesN;
  const int tid = threadIdx.x;
  const int lane = tid & 63, w = tid >> 6;
  const int l15 = lane & 15, quad = lane >> 4;

  // LDS: double-buffered A(64x32) + B(128x32) bf16 tiles = 24 KB
  __shared__ bf16 As[2][64 * 32];
  __shared__ bf16 Bs[2][128 * 32];

  f32x4 acc[4][2];
#pragma unroll
  for (int i = 0; i < 4; ++i)
#pragma unroll
    for (int j = 0; j < 2; ++j) acc[i][j] = (f32x4){0.f, 0.f, 0.f, 0.f};

  // Per-wave staging: wave w covers A rows [w*16, w*16+16) and
  // B rows [w*16, w*16+16) + [64+w*16, 64+w*16+16).
  // HW writes lane's 16B at ldsbase + lane*16 -> row w*16 + lane/4, col (lane&3)*8.
  const bf16* gA  = J.A + (size_t)(tm * 64 + w * 16 + (lane >> 2)) * J.K + (lane & 3) * 8;
  const bf16* gB0 = J.B + (size_t)(tn * 128 + w * 16 + (lane >> 2)) * J.K + (lane & 3) * 8;
  const bf16* gB1 = gB0 + (size_t)64 * J.K;

  auto stage = [&](int buf, int kt) {
    int k0 = kt << 5;
    gll16(gA + k0, &As[buf][w * 512]);
    gll16(gB0 + k0, &Bs[buf][w * 512]);
    gll16(gB1 + k0, &Bs[buf][2048 + w * 512]);
  };

  int nt = J.K >> 5;
  int cur = 0;
  stage(0, 0);
  if (nt > 1) stage(1, 1);

  for (int tt = 0; tt < nt; ++tt) {
    // wait for tile tt's 3 per-wave loads (leave next tile's 3 in flight)
    if (tt + 1 < nt) asm volatile("s_waitcnt vmcnt(3)" ::: "memory");
    else             asm volatile("s_waitcnt vmcnt(0)" ::: "memory");
    __builtin_amdgcn_sched_barrier(0);
    __builtin_amdgcn_s_barrier();   // all waves' chunks landed

    const bf16* Ab = As[cur];
    const bf16* Bb = Bs[cur];
    bf16x8 af[4], bw[2];
#pragma unroll
    for (int i = 0; i < 4; ++i)
      af[i] = *(const bf16x8*)(Ab + (i * 16 + l15) * 32 + quad * 8);
#pragma unroll
    for (int j = 0; j < 2; ++j)
      bw[j] = *(const bf16x8*)(Bb + (w * 32 + j * 16 + l15) * 32 + quad * 8);
    asm volatile("s_waitcnt lgkmcnt(0)" ::: "memory");
    __builtin_amdgcn_sched_barrier(0);
    __builtin_amdgcn_s_barrier();   // all waves done reading buf[cur]

    if (tt + 2 < nt) stage(cur, tt + 2);  // overwrite freed buffer, 2 ahead

#pragma unroll
    for (int i = 0; i < 4; ++i)
#pragma unroll
      for (int j = 0; j < 2; ++j) acc[i][j] = mfma16(af[i], bw[j], acc[i][j]);
    cur ^= 1;
  }

#pragma unroll
  for (int i = 0; i < 4; ++i)
#pragma unroll
    for (int j = 0; j < 2; ++j) {
      int row0 = tm * 64 + i * 16 + quad * 4;
      int col = tn * 128 + w * 32 + j * 16 + l15;
#pragma unroll
      for (int r = 0; r < 4; ++r) {
        size_t idx = (size_t)(row0 + r) * J.N + col;
        if (J.addFlag) J.C[idx] += acc[i][j][r];
        else J.C[idx] = acc[i][j][r];
      }
    }
}

// ---------------- rope(Q,K)->bf16 and V transpose -> Vt[h*64+d][key] --------
__global__ __launch_bounds__(256) void rope_vt_kernel(const float* qkv, const float* cosT,
                                                      const float* sinT, bf16* Qb,
                                                      bf16* Kb, bf16* Vt) {
  int b = blockIdx.x;
  if (b < 2688) {
    bool isQ = b < 1280;
    int r = isQ ? b : b - 1280;
    const float* x = qkv + (size_t)(isQ ? r : 1280 + r) * DM;
    int pos = isQ ? (r < 1152 ? r + 128 : r) : (r < 1280 ? r : r - 128);
    bf16* out = (isQ ? Qb : Kb) + (size_t)r * DM;
#pragma unroll
    for (int it = 0; it < 4; ++it) {
      int g = threadIdx.x + it * 256;
      int idx = g & 31;
      float c = cosT[pos * 32 + idx], s = sinT[pos * 32 + idx];
      float xv = x[g];
      float rot = ((g & 63) < 32) ? -x[g + 32] : x[g - 32];
      out[g] = (bf16)(xv * c + rot * s);
    }
  } else {
    int t = b - 2688;           // 44 x 32 tiles over V (1408 keys x 1024 dims)
    int tk = t >> 5, td = t & 31;
    int key0 = tk * 32, d0 = td * 32;
    __shared__ float tile[32][33];
    int c = threadIdx.x & 31, r0 = threadIdx.x >> 5;
#pragma unroll
    for (int i = 0; i < 4; ++i) {
      int r = r0 + i * 8;
      tile[r][c] = qkv[(size_t)(2688 + key0 + r) * DM + d0 + c];
    }
    __syncthreads();
#pragma unroll
    for (int i = 0; i < 4; ++i) {
      int r = r0 + i * 8;
      Vt[(size_t)(d0 + r) * NKV + key0 + c] = (bf16)tile[c][r];
    }
  }
}

// ---------------- flash attention (1 wave / 16-query tile) ------------------
__global__ __launch_bounds__(64) void attn_kernel(const bf16* Qb, const bf16* Kb,
                                                  const bf16* Vt, bf16* Ob) {
  int b = blockIdx.x;
  int h, q0, qRow0, maskBase, extraOff, kmax;
  if (b < 1024) {            // hidden queries
    h = b >> 6; q0 = (b & 63) << 4; qRow0 = 0; maskBase = 128; extraOff = 0;
    kmax = 128 + q0 + 16; if (kmax > 1152) kmax = 1152;
  } else if (b < 1152) {     // beacon gate
    int i = b - 1024; h = i >> 3; q0 = (i & 7) << 4; qRow0 = 1024;
    maskBase = 1152; extraOff = 0; kmax = 1152 + q0 + 16;
  } else {                   // forget gate (extra keys live at rows +128)
    int i = b - 1152; h = i >> 3; q0 = (i & 7) << 4; qRow0 = 1152;
    maskBase = 1152; extraOff = 128; kmax = 1152 + q0 + 16;
  }
  const int lane = threadIdx.x;
  const int l15 = lane & 15, quad = lane >> 4;
  const bf16* qp = Qb + (size_t)(qRow0 + q0 + l15) * DM + h * 64 + quad * 8;
  bf16x8 aq0 = *(const bf16x8*)qp;
  bf16x8 aq1 = *(const bf16x8*)(qp + 32);
  f32x4 O0 = {0,0,0,0}, O1 = {0,0,0,0}, O2 = {0,0,0,0}, O3 = {0,0,0,0};
  float mrow[4], lrow[4];
#pragma unroll
  for (int r = 0; r < 4; ++r) { mrow[r] = -3.0e38f; lrow[r] = 0.f; }
  __shared__ bf16 Plds[16][32];
  int nkt = (kmax + 31) >> 5;
  for (int kt = 0; kt < nkt; ++kt) {
    int k0 = kt << 5;
    int off = (k0 >= 1152) ? extraOff : 0;
    f32x4 s0 = {0,0,0,0}, s1 = {0,0,0,0};
    {
      const bf16* kp = Kb + (size_t)(k0 + l15 + off) * DM + h * 64 + quad * 8;
      s0 = mfma16(aq0, *(const bf16x8*)kp, s0);
      s0 = mfma16(aq1, *(const bf16x8*)(kp + 32), s0);
      const bf16* kp1 = kp + (size_t)16 * DM;
      s1 = mfma16(aq0, *(const bf16x8*)kp1, s1);
      s1 = mfma16(aq1, *(const bf16x8*)(kp1 + 32), s1);
    }
    float p0[4], p1[4], mt[4];
#pragma unroll
    for (int r = 0; r < 4; ++r) {
      int qi = q0 + quad * 4 + r;
      int key0k = k0 + l15;
      int key1k = key0k + 16;
      float v0 = s0[r] * 0.125f, v1 = s1[r] * 0.125f;
      if (!(key0k < maskBase || key0k - maskBase <= qi)) v0 = -3.0e38f;
      if (!(key1k < maskBase || key1k - maskBase <= qi)) v1 = -3.0e38f;
      p0[r] = v0; p1[r] = v1;
      mt[r] = fmaxf(v0, v1);
    }
#pragma unroll
    for (int d = 1; d < 16; d <<= 1) {
#pragma unroll
      for (int r = 0; r < 4; ++r) mt[r] = fmaxf(mt[r], __shfl_xor(mt[r], d, 64));
    }
    float alpha[4];
#pragma unroll
    for (int r = 0; r < 4; ++r) {
      float mn = fmaxf(mrow[r], mt[r]);
      alpha[r] = __expf(mrow[r] - mn);
      mrow[r] = mn;
      p0[r] = __expf(p0[r] - mn);
      p1[r] = __expf(p1[r] - mn);
    }
    float rs[4];
#pragma unroll
    for (int r = 0; r < 4; ++r) rs[r] = p0[r] + p1[r];
#pragma unroll
    for (int d = 1; d < 16; d <<= 1) {
#pragma unroll
      for (int r = 0; r < 4; ++r) rs[r] += __shfl_xor(rs[r], d, 64);
    }
#pragma unroll
    for (int r = 0; r < 4; ++r) {
      lrow[r] = lrow[r] * alpha[r] + rs[r];
      O0[r] *= alpha[r]; O1[r] *= alpha[r]; O2[r] *= alpha[r]; O3[r] *= alpha[r];
    }
    __syncthreads();
#pragma unroll
    for (int r = 0; r < 4; ++r) {
      Plds[quad * 4 + r][l15] = (bf16)p0[r];
      Plds[quad * 4 + r][l15 + 16] = (bf16)p1[r];
    }
    __syncthreads();
    bf16x8 ap = *(const bf16x8*)(&Plds[l15][quad * 8]);
    const bf16* vp = Vt + (size_t)(h * 64 + l15) * NKV + k0 + off + quad * 8;
    O0 = mfma16(ap, *(const bf16x8*)vp, O0);
    O1 = mfma16(ap, *(const bf16x8*)(vp + (size_t)16 * NKV), O1);
    O2 = mfma16(ap, *(const bf16x8*)(vp + (size_t)32 * NKV), O2);
    O3 = mfma16(ap, *(const bf16x8*)(vp + (size_t)48 * NKV), O3);
  }
#pragma unroll
  for (int r = 0; r < 4; ++r) lrow[r] = 1.0f / lrow[r];
  bf16* op = Ob + (size_t)(qRow0 + q0 + quad * 4) * DM + h * 64 + l15;
#pragma unroll
  for (int r = 0; r < 4; ++r) {
    float inv = lrow[r];
    op[(size_t)r * DM + 0]  = (bf16)(O0[r] * inv);
    op[(size_t)r * DM + 16] = (bf16)(O1[r] * inv);
    op[(size_t)r * DM + 32] = (bf16)(O2[r] * inv);
    op[(size_t)r * DM + 48] = (bf16)(O3[r] * inv);
  }
}

// ---------------- silu(G)*U -> bf16 -----------------------------------------
__global__ void silu_kernel(const float* G, const float* U, bf16* H) {
  size_t i = (size_t)blockIdx.x * 256 + threadIdx.x;
  f32x4 g = *(const f32x4*)(G + i * 4);
  f32x4 u = *(const f32x4*)(U + i * 4);
  bf16* o = H + i * 4;
#pragma unroll
  for (int r = 0; r < 4; ++r) {
    float gv = g[r];
    float s = gv / (1.f + __expf(-gv));
    o[r] = (bf16)(s * u[r]);
  }
}

// ---------------- workspace layout (bytes) ----------------------------------
static const size_t OFF_COS = 0;           // 1280*32*4
static const size_t OFF_SIN = 163840;
static const size_t OFF_CAT = 327680;      // 1280*1024 f32
static const size_t OFF_XB  = 5570560;     // 1408*1024 bf16 (normed x + mem)
static const size_t OFF_QKV = 8454144;     // 4096*1024 f32
static const size_t OFF_QB  = 25231360;    // 1280*1024 bf16
static const size_t OFF_KB  = 27852800;    // 1408*1024 bf16
static const size_t OFF_VT  = 30736384;    // 1024*1408 bf16
static const size_t OFF_OB  = 33619968;    // 1280*1024 bf16
static const size_t OFF_YB  = 36241408;    // 1280*1024 bf16
static const size_t OFF_WT  = 38862848;    // 18M elems bf16 transposed weights
static const size_t OFF_G   = 76611584;    // 1280*2048 f32
static const size_t OFF_U   = 87097344;    // 1280*2048 f32
static const size_t OFF_HB  = 97583104;    // 1280*2048 bf16
// total ~102.8 MB

extern "C" void kernel_launch(void* const* d_in, const int* in_sizes, int n_in,
                              void* d_out, int out_size, void* d_ws, size_t ws_size,
                              hipStream_t stream) {
  const int* ids = (const int*)d_in[0];
  const float* memory = (const float*)d_in[1];
  const float* beacon = (const float*)d_in[2];
  const float* forget = (const float*)d_in[3];
  const float* embed = (const float*)d_in[4];
  const float* ln1 = (const float*)d_in[5];
  const float* ln2 = (const float*)d_in[6];
  const float* Wq = (const float*)d_in[7];
  const float* Wk = (const float*)d_in[8];
  const float* Wv = (const float*)d_in[9];
  const float* Wo = (const float*)d_in[10];
  const float* mWk = (const float*)d_in[11];
  const float* mWv = (const float*)d_in[12];
  const float* bWq = (const float*)d_in[13];
  const float* bWk = (const float*)d_in[14];
  const float* bWv = (const float*)d_in[15];
  const float* fWq = (const float*)d_in[16];
  const float* fWk = (const float*)d_in[17];
  const float* fWv = (const float*)d_in[18];
  const float* Wg = (const float*)d_in[19];
  const float* Wu = (const float*)d_in[20];
  const float* Wd = (const float*)d_in[21];

  char* wsb = (char*)d_ws;
  float* cosT = (float*)(wsb + OFF_COS);
  float* sinT = (float*)(wsb + OFF_SIN);
  float* cat  = (float*)(wsb + OFF_CAT);
  bf16* xb    = (bf16*)(wsb + OFF_XB);
  float* qkv  = (float*)(wsb + OFF_QKV);
  bf16* Qb    = (bf16*)(wsb + OFF_QB);
  bf16* Kb    = (bf16*)(wsb + OFF_KB);
  bf16* Vt    = (bf16*)(wsb + OFF_VT);
  bf16* Ob    = (bf16*)(wsb + OFF_OB);
  bf16* yb    = (bf16*)(wsb + OFF_YB);
  bf16* wt    = (bf16*)(wsb + OFF_WT);
  float* Gf   = (float*)(wsb + OFF_G);
  float* Uf   = (float*)(wsb + OFF_U);
  bf16* Hb    = (bf16*)(wsb + OFF_HB);
  float* outp = (float*)d_out;

  // tiles are 64 (M) x 128 (N)
  auto mkjob = [](const bf16* A, const bf16* B, float* C, int K, int N, int M,
                  int addFlag, int& tiles) {
    GemmJob j; j.A = A; j.B = B; j.C = C; j.K = K; j.N = N;
    j.tileStart = tiles; j.addFlag = addFlag;
    tiles += (M / 64) * (N / 128);
    return j;
  };

  rope_table_kernel<<<1280, 32, 0, stream>>>(cosT, sinT);
  init_cat_kernel<<<1280, 256, 0, stream>>>(ids, embed, beacon, forget, cat);

  for (int l = 0; l < 8; ++l) {
    out_gate_kernel<<<128, 256, 0, stream>>>(cat, memory + (size_t)l * 131072,
                                             outp + (size_t)l * 131072);
    if (l == 7) break;  // layer 7's transform never affects outputs

    // ---- transpose+convert this layer's weights to bf16 (N x K) ----
    TransArgs ta; int tt = 0;
    const float* s12[12] = {Wq, Wk, Wv, Wo, mWk, mWv, bWq, bWk, bWv, fWq, fWk, fWv};
    for (int i = 0; i < 12; ++i) {
      ta.j[i].src = s12[i] + (size_t)l * 1048576;
      ta.j[i].dst = wt + (size_t)i * 1048576;
      ta.j[i].K = 1024; ta.j[i].N = 1024; ta.j[i].tileStart = tt; tt += 1024;
    }
    ta.j[12].src = Wg + (size_t)l * 2097152; ta.j[12].dst = wt + (size_t)12 * 1048576;
    ta.j[12].K = 1024; ta.j[12].N = 2048; ta.j[12].tileStart = tt; tt += 2048;
    ta.j[13].src = Wu + (size_t)l * 2097152; ta.j[13].dst = wt + (size_t)14 * 1048576;
    ta.j[13].K = 1024; ta.j[13].N = 2048; ta.j[13].tileStart = tt; tt += 2048;
    ta.j[14].src = Wd + (size_t)l * 2097152; ta.j[14].dst = wt + (size_t)16 * 1048576;
    ta.j[14].K = 2048; ta.j[14].N = 1024; ta.j[14].tileStart = tt; tt += 2048;
    ta.njobs = 15;
    trans_kernel<<<tt, 256, 0, stream>>>(ta);

    // ---- rmsnorm(cat, ln1) -> xb rows 0..1279; memory[l] -> rows 1280..1407
    rmsnorm_kernel<<<1408, 256, 0, stream>>>(cat, ln1 + (size_t)l * 1024, xb,
                                             memory + (size_t)l * 131072, 1280);

    // ---- 11 projection GEMMs into qkv buffer ----
    auto xrow = [&](int r) { return xb + (size_t)r * DM; };
    auto crow = [&](int r) { return qkv + (size_t)r * DM; };
    auto wtm = [&](int i) { return wt + (size_t)i * 1048576; };
    GemmArgs ga; int tA = 0; int nj = 0;
    ga.j[nj++] = mkjob(xrow(0),    wtm(0),  crow(0),    1024, 1024, 1024, 0, tA); // Qh
    ga.j[nj++] = mkjob(xrow(1024), wtm(6),  crow(1024), 1024, 1024, 128, 0, tA);  // bQ
    ga.j[nj++] = mkjob(xrow(1152), wtm(9),  crow(1152), 1024, 1024, 128, 0, tA);  // fQ
    ga.j[nj++] = mkjob(xrow(1280), wtm(4),  crow(1280), 1024, 1024, 128, 0, tA);  // mK
    ga.j[nj++] = mkjob(xrow(0),    wtm(1),  crow(1408), 1024, 1024, 1024, 0, tA); // Kh
    ga.j[nj++] = mkjob(xrow(1024), wtm(7),  crow(2432), 1024, 1024, 128, 0, tA);  // bK
    ga.j[nj++] = mkjob(xrow(1152), wtm(10), crow(2560), 1024, 1024, 128, 0, tA);  // fK
    ga.j[nj++] = mkjob(xrow(1280), wtm(5),  crow(2688), 1024, 1024, 128, 0, tA);  // mV
    ga.j[nj++] = mkjob(xrow(0),    wtm(2),  crow(2816), 1024, 1024, 1024, 0, tA); // Vh
    ga.j[nj++] = mkjob(xrow(1024), wtm(8),  crow(3840), 1024, 1024, 128, 0, tA);  // bV
    ga.j[nj++] = mkjob(xrow(1152), wtm(11), crow(3968), 1024, 1024, 128, 0, tA);  // fV
    ga.njobs = nj;
    gemm_kernel<<<tA, 256, 0, stream>>>(ga);

    // ---- rope Q/K -> bf16, transpose V -> Vt ----
    rope_vt_kernel<<<4096, 256, 0, stream>>>(qkv, cosT, sinT, Qb, Kb, Vt);

    // ---- attention (hidden + beacon + forget) ----
    attn_kernel<<<1280, 64, 0, stream>>>(Qb, Kb, Vt, Ob);

    // ---- O @ Wo, add into cat ----
    GemmArgs gb; int tB = 0;
    gb.j[0] = mkjob(Ob, wtm(3), cat, 1024, 1024, 1280, 1, tB);
    gb.njobs = 1;
    gemm_kernel<<<tB, 256, 0, stream>>>(gb);

    // ---- rmsnorm2 -> yb ----
    rmsnorm_kernel<<<1280, 256, 0, stream>>>(cat, ln2 + (size_t)l * 1024, yb,
                                             nullptr, 1280);

    // ---- FFN: G = y@Wg, U = y@Wu ----
    GemmArgs gc; int tC = 0;
    gc.j[0] = mkjob(yb, wtm(12), Gf, 1024, 2048, 1280, 0, tC);
    gc.j[1] = mkjob(yb, wtm(14), Uf, 1024, 2048, 1280, 0, tC);
    gc.njobs = 2;
    gemm_kernel<<<tC, 256, 0, stream>>>(gc);

    silu_kernel<<<2560, 256, 0, stream>>>(Gf, Uf, Hb);

    // ---- H @ Wd, add into cat ----
    GemmArgs gd; int tD = 0;
    gd.j[0] = mkjob(Hb, wtm(16), cat, 2048, 1024, 1280, 1, tD);
    gd.njobs = 1;
    gemm_kernel<<<tD, 256, 0, stream>>>(gd);
  }
}

// Round 2
// 1809.946 us; speedup vs baseline: 1.2678x; 1.0427x over previous
//
#include <hip/hip_runtime.h>
#include <math.h>

typedef __bf16 bf16;
typedef __attribute__((ext_vector_type(8))) __bf16 bf16x8;
typedef __attribute__((ext_vector_type(4))) float f32x4;

// Model dims
static const int DM = 1024;   // D
static const int TCAT = 1280; // S + 2M
static const int NKV = 1408;  // mem(128)+hid(1024)+bK(128)+fK(128)

__device__ inline f32x4 mfma16(bf16x8 a, bf16x8 b, f32x4 c) {
  return __builtin_amdgcn_mfma_f32_16x16x32_bf16(a, b, c, 0, 0, 0);
}

// ---------------- RoPE tables (fp64 on device, matches np.float64 ref) ------
__global__ void rope_table_kernel(float* cosT, float* sinT) {
  int p = blockIdx.x, i = threadIdx.x; // 1280 x 32
  double freq = pow(10000.0, -((double)i) / 32.0);
  double a = (double)p * freq;
  cosT[p * 32 + i] = (float)cos(a);
  sinT[p * 32 + i] = (float)sin(a);
}

// ---------------- cat init: [embed[ids]; beacon; forget] --------------------
__global__ void init_cat_kernel(const int* ids, const float* embed,
                                const float* beacon, const float* forget,
                                float* cat) {
  int r = blockIdx.x, tid = threadIdx.x;
  const float* src;
  if (r < 1024) src = embed + (size_t)ids[r] * DM;
  else if (r < 1152) src = beacon + (size_t)(r - 1024) * DM;
  else src = forget + (size_t)(r - 1152) * DM;
  *(f32x4*)(cat + (size_t)r * DM + tid * 4) = *(const f32x4*)(src + tid * 4);
}

// ---------------- out[l] = mem*g + inj*(1-g), from carry at layer entry -----
__global__ void out_gate_kernel(const float* cat, const float* memL, float* outL) {
  int m = blockIdx.x, tid = threadIdx.x;
  size_t c = (size_t)tid * 4;
  f32x4 f = *(const f32x4*)(cat + (size_t)(1152 + m) * DM + c);
  f32x4 j = *(const f32x4*)(cat + (size_t)(1024 + m) * DM + c);
  f32x4 mm = *(const f32x4*)(memL + (size_t)m * DM + c);
  f32x4 o;
#pragma unroll
  for (int r = 0; r < 4; ++r) {
    float g = 1.f / (1.f + __expf(-f[r]));
    o[r] = mm[r] * g + j[r] * (1.f - g);
  }
  *(f32x4*)(outL + (size_t)m * DM + c) = o;
}

// ---------------- weight transpose + f32->bf16 ------------------------------
struct TransJob { const float* src; bf16* dst; int K; int N; int tileStart; };
struct TransArgs { TransJob j[15]; int njobs; };

__global__ __launch_bounds__(256) void trans_kernel(TransArgs args) {
  int b = blockIdx.x, ji = 0;
  while (ji + 1 < args.njobs && b >= args.j[ji + 1].tileStart) ++ji;
  TransJob J = args.j[ji];
  int t = b - J.tileStart;
  int tilesN = J.N >> 5;
  int tk = t / tilesN, tn = t - tk * tilesN;
  int k0 = tk * 32, n0 = tn * 32;
  __shared__ float tile[32][33];
  int c = threadIdx.x & 31, r0 = threadIdx.x >> 5;
#pragma unroll
  for (int i = 0; i < 4; ++i) {
    int r = r0 + i * 8;
    tile[r][c] = J.src[(size_t)(k0 + r) * J.N + n0 + c];
  }
  __syncthreads();
#pragma unroll
  for (int i = 0; i < 4; ++i) {
    int r = r0 + i * 8;
    J.dst[(size_t)(n0 + r) * J.K + k0 + c] = (bf16)tile[c][r];
  }
}

// ---------------- rmsnorm (fp32) -> bf16; tail rows = raw memory convert ----
__global__ __launch_bounds__(256) void rmsnorm_kernel(const float* x, const float* w,
                                                      bf16* out, const float* mem,
                                                      int nNorm) {
  int r = blockIdx.x, tid = threadIdx.x;
  if (r < nNorm) {
    f32x4 v = *(const f32x4*)(x + (size_t)r * DM + tid * 4);
    float ss = v[0] * v[0] + v[1] * v[1] + v[2] * v[2] + v[3] * v[3];
#pragma unroll
    for (int d = 1; d < 64; d <<= 1) ss += __shfl_xor(ss, d, 64);
    __shared__ float red[4];
    if ((tid & 63) == 0) red[tid >> 6] = ss;
    __syncthreads();
    float tot = red[0] + red[1] + red[2] + red[3];
    float scale = rsqrtf(tot * (1.0f / 1024.0f) + 1e-5f);
    f32x4 wv = *(const f32x4*)(w + tid * 4);
    bf16* o = out + (size_t)r * DM + tid * 4;
#pragma unroll
    for (int q = 0; q < 4; ++q) o[q] = (bf16)(v[q] * wv[q] * scale);
  } else {
    f32x4 v = *(const f32x4*)(mem + (size_t)(r - nNorm) * DM + tid * 4);
    bf16* o = out + (size_t)r * DM + tid * 4;
#pragma unroll
    for (int q = 0; q < 4; ++q) o[q] = (bf16)v[q];
  }
}

// ---------------- grouped bf16 GEMM -----------------------------------------
// 64x128 tiles, global_load_lds(16B) staging, LDS dbuf, depth-2 counted vmcnt.
// modes: 0 = store f32, 1 = add f32 (RMW), 2 = store bf16,
//        3 = dual-panel FFN: silu(A@B)*(A@B2) -> bf16
//        4 = atomicAdd f32 (for kSplit>1 accumulation)
struct GemmJob {
  const bf16* A; const bf16* B; const bf16* B2; void* C;
  int K; int N; int ldC; int tileStart; int nMN; int mode; int kSplit;
};
struct GemmArgs { GemmJob j[12]; int njobs; };

__device__ __forceinline__ void gll16(const bf16* g, bf16* l) {
  __builtin_amdgcn_global_load_lds(
      (const __attribute__((address_space(1))) void*)g,
      (__attribute__((address_space(3))) void*)l, 16, 0, 0);
}

__global__ __launch_bounds__(256, 2) void gemm_kernel(GemmArgs args) {
  int b = blockIdx.x, ji = 0;
  while (ji + 1 < args.njobs && b >= args.j[ji + 1].tileStart) ++ji;
  GemmJob J = args.j[ji];
  int t = b - J.tileStart;
  int ks = 0;
  if (J.kSplit > 1) { ks = t / J.nMN; t -= ks * J.nMN; }
  int tilesN = J.N >> 7;
  int tm = t / tilesN, tn = t - tm * tilesN;
  int kLen = J.K / J.kSplit;
  int kBase = ks * kLen;
  const int tid = threadIdx.x;
  const int lane = tid & 63, w = tid >> 6;
  const int l15 = lane & 15, quad = lane >> 4;
  const bool ffn = (J.mode == 3);

  // double-buffered LDS tiles (40 KB total; 2 blocks/CU)
  __shared__ bf16 As[2][64 * 32];
  __shared__ bf16 Bs[2][128 * 32];
  __shared__ bf16 B2s[2][128 * 32];

  f32x4 acc[4][2], acc2[4][2];
#pragma unroll
  for (int i = 0; i < 4; ++i)
#pragma unroll
    for (int j = 0; j < 2; ++j) {
      acc[i][j] = (f32x4){0.f, 0.f, 0.f, 0.f};
      acc2[i][j] = (f32x4){0.f, 0.f, 0.f, 0.f};
    }

  // per-wave staging addresses (linear LDS, lane*16B HW pattern)
  const bf16* gA  = J.A + (size_t)(tm * 64 + w * 16 + (lane >> 2)) * J.K + (lane & 3) * 8 + kBase;
  const bf16* gB0 = J.B + (size_t)(tn * 128 + w * 16 + (lane >> 2)) * J.K + (lane & 3) * 8 + kBase;
  const bf16* gB1 = gB0 + (size_t)64 * J.K;
  const bf16* gC0 = J.B2 + (size_t)(tn * 128 + w * 16 + (lane >> 2)) * J.K + (lane & 3) * 8 + kBase;
  const bf16* gC1 = gC0 + (size_t)64 * J.K;

  auto stage = [&](int buf, int kt) {
    int k0 = kt << 5;
    gll16(gA + k0, &As[buf][w * 512]);
    gll16(gB0 + k0, &Bs[buf][w * 512]);
    gll16(gB1 + k0, &Bs[buf][2048 + w * 512]);
    if (ffn) {
      gll16(gC0 + k0, &B2s[buf][w * 512]);
      gll16(gC1 + k0, &B2s[buf][2048 + w * 512]);
    }
  };

  int nt = kLen >> 5;
  int cur = 0;
  stage(0, 0);
  if (nt > 1) stage(1, 1);

  for (int tt = 0; tt < nt; ++tt) {
    if (tt + 1 < nt) {
      if (ffn) asm volatile("s_waitcnt vmcnt(5)" ::: "memory");
      else     asm volatile("s_waitcnt vmcnt(3)" ::: "memory");
    } else {
      asm volatile("s_waitcnt vmcnt(0)" ::: "memory");
    }
    __builtin_amdgcn_sched_barrier(0);
    __builtin_amdgcn_s_barrier();   // tile tt landed for all waves

    const bf16* Ab = As[cur];
    const bf16* Bb = Bs[cur];
    const bf16* B2b = B2s[cur];
    bf16x8 af[4], bw[2], bw2[2];
#pragma unroll
    for (int i = 0; i < 4; ++i)
      af[i] = *(const bf16x8*)(Ab + (i * 16 + l15) * 32 + quad * 8);
#pragma unroll
    for (int j = 0; j < 2; ++j)
      bw[j] = *(const bf16x8*)(Bb + (w * 32 + j * 16 + l15) * 32 + quad * 8);
    if (ffn) {
#pragma unroll
      for (int j = 0; j < 2; ++j)
        bw2[j] = *(const bf16x8*)(B2b + (w * 32 + j * 16 + l15) * 32 + quad * 8);
    }
    asm volatile("s_waitcnt lgkmcnt(0)" ::: "memory");
    __builtin_amdgcn_sched_barrier(0);
    __builtin_amdgcn_s_barrier();   // all waves done reading buf[cur]

    if (tt + 2 < nt) stage(cur, tt + 2);  // refill freed buffer, depth 2

#pragma unroll
    for (int i = 0; i < 4; ++i)
#pragma unroll
      for (int j = 0; j < 2; ++j) acc[i][j] = mfma16(af[i], bw[j], acc[i][j]);
    if (ffn) {
#pragma unroll
      for (int i = 0; i < 4; ++i)
#pragma unroll
        for (int j = 0; j < 2; ++j) acc2[i][j] = mfma16(af[i], bw2[j], acc2[i][j]);
    }
    cur ^= 1;
  }

  // ---- epilogue ----
#pragma unroll
  for (int i = 0; i < 4; ++i)
#pragma unroll
    for (int j = 0; j < 2; ++j) {
      int row0 = tm * 64 + i * 16 + quad * 4;
      int col = tn * 128 + w * 32 + j * 16 + l15;
#pragma unroll
      for (int r = 0; r < 4; ++r) {
        size_t idx = (size_t)(row0 + r) * J.ldC + col;
        float v = acc[i][j][r];
        if (J.mode == 0) {
          ((float*)J.C)[idx] = v;
        } else if (J.mode == 1) {
          ((float*)J.C)[idx] += v;
        } else if (J.mode == 2) {
          ((bf16*)J.C)[idx] = (bf16)v;
        } else if (J.mode == 3) {
          float u = acc2[i][j][r];
          float s = v / (1.f + __expf(-v));
          ((bf16*)J.C)[idx] = (bf16)(s * u);
        } else { // mode 4: atomic accumulate (kSplit)
          atomicAdd((float*)J.C + idx, v);
        }
      }
    }
}

// ---------------- rope(Q,K)->bf16 (V handled by GEMM now) -------------------
__global__ __launch_bounds__(256) void rope_vt_kernel(const float* qkv, const float* cosT,
                                                      const float* sinT, bf16* Qb,
                                                      bf16* Kb) {
  int b = blockIdx.x;
  bool isQ = b < 1280;
  int r = isQ ? b : b - 1280;
  const float* x = qkv + (size_t)(isQ ? r : 1280 + r) * DM;
  int pos = isQ ? (r < 1152 ? r + 128 : r) : (r < 1280 ? r : r - 128);
  bf16* out = (isQ ? Qb : Kb) + (size_t)r * DM;
#pragma unroll
  for (int it = 0; it < 4; ++it) {
    int g = threadIdx.x + it * 256;
    int idx = g & 31;
    float c = cosT[pos * 32 + idx], s = sinT[pos * 32 + idx];
    float xv = x[g];
    float rot = ((g & 63) < 32) ? -x[g + 32] : x[g - 32];
    out[g] = (bf16)(xv * c + rot * s);
  }
}

// ---------------- flash attention (1 wave / 16-query tile) ------------------
__global__ __launch_bounds__(64) void attn_kernel(const bf16* Qb, const bf16* Kb,
                                                  const bf16* Vt, bf16* Ob) {
  int b = blockIdx.x;
  int h, q0, qRow0, maskBase, extraOff, kmax;
  if (b < 1024) {            // hidden queries
    h = b >> 6; q0 = (b & 63) << 4; qRow0 = 0; maskBase = 128; extraOff = 0;
    kmax = 128 + q0 + 16; if (kmax > 1152) kmax = 1152;
  } else if (b < 1152) {     // beacon gate
    int i = b - 1024; h = i >> 3; q0 = (i & 7) << 4; qRow0 = 1024;
    maskBase = 1152; extraOff = 0; kmax = 1152 + q0 + 16;
  } else {                   // forget gate (extra keys live at rows +128)
    int i = b - 1152; h = i >> 3; q0 = (i & 7) << 4; qRow0 = 1152;
    maskBase = 1152; extraOff = 128; kmax = 1152 + q0 + 16;
  }
  const int lane = threadIdx.x;
  const int l15 = lane & 15, quad = lane >> 4;
  const bf16* qp = Qb + (size_t)(qRow0 + q0 + l15) * DM + h * 64 + quad * 8;
  bf16x8 aq0 = *(const bf16x8*)qp;
  bf16x8 aq1 = *(const bf16x8*)(qp + 32);
  f32x4 O0 = {0,0,0,0}, O1 = {0,0,0,0}, O2 = {0,0,0,0}, O3 = {0,0,0,0};
  float mrow[4], lrow[4];
#pragma unroll
  for (int r = 0; r < 4; ++r) { mrow[r] = -3.0e38f; lrow[r] = 0.f; }
  __shared__ bf16 Plds[16][32];
  int nkt = (kmax + 31) >> 5;
  for (int kt = 0; kt < nkt; ++kt) {
    int k0 = kt << 5;
    int off = (k0 >= 1152) ? extraOff : 0;
    f32x4 s0 = {0,0,0,0}, s1 = {0,0,0,0};
    {
      const bf16* kp = Kb + (size_t)(k0 + l15 + off) * DM + h * 64 + quad * 8;
      s0 = mfma16(aq0, *(const bf16x8*)kp, s0);
      s0 = mfma16(aq1, *(const bf16x8*)(kp + 32), s0);
      const bf16* kp1 = kp + (size_t)16 * DM;
      s1 = mfma16(aq0, *(const bf16x8*)kp1, s1);
      s1 = mfma16(aq1, *(const bf16x8*)(kp1 + 32), s1);
    }
    float p0[4], p1[4], mt[4];
#pragma unroll
    for (int r = 0; r < 4; ++r) {
      int qi = q0 + quad * 4 + r;
      int key0k = k0 + l15;
      int key1k = key0k + 16;
      float v0 = s0[r] * 0.125f, v1 = s1[r] * 0.125f;
      if (!(key0k < maskBase || key0k - maskBase <= qi)) v0 = -3.0e38f;
      if (!(key1k < maskBase || key1k - maskBase <= qi)) v1 = -3.0e38f;
      p0[r] = v0; p1[r] = v1;
      mt[r] = fmaxf(v0, v1);
    }
#pragma unroll
    for (int d = 1; d < 16; d <<= 1) {
#pragma unroll
      for (int r = 0; r < 4; ++r) mt[r] = fmaxf(mt[r], __shfl_xor(mt[r], d, 64));
    }
    float alpha[4];
#pragma unroll
    for (int r = 0; r < 4; ++r) {
      float mn = fmaxf(mrow[r], mt[r]);
      alpha[r] = __expf(mrow[r] - mn);
      mrow[r] = mn;
      p0[r] = __expf(p0[r] - mn);
      p1[r] = __expf(p1[r] - mn);
    }
    float rs[4];
#pragma unroll
    for (int r = 0; r < 4; ++r) rs[r] = p0[r] + p1[r];
#pragma unroll
    for (int d = 1; d < 16; d <<= 1) {
#pragma unroll
      for (int r = 0; r < 4; ++r) rs[r] += __shfl_xor(rs[r], d, 64);
    }
#pragma unroll
    for (int r = 0; r < 4; ++r) {
      lrow[r] = lrow[r] * alpha[r] + rs[r];
      O0[r] *= alpha[r]; O1[r] *= alpha[r]; O2[r] *= alpha[r]; O3[r] *= alpha[r];
    }
    __syncthreads();
#pragma unroll
    for (int r = 0; r < 4; ++r) {
      Plds[quad * 4 + r][l15] = (bf16)p0[r];
      Plds[quad * 4 + r][l15 + 16] = (bf16)p1[r];
    }
    __syncthreads();
    bf16x8 ap = *(const bf16x8*)(&Plds[l15][quad * 8]);
    const bf16* vp = Vt + (size_t)(h * 64 + l15) * NKV + k0 + off + quad * 8;
    O0 = mfma16(ap, *(const bf16x8*)vp, O0);
    O1 = mfma16(ap, *(const bf16x8*)(vp + (size_t)16 * NKV), O1);
    O2 = mfma16(ap, *(const bf16x8*)(vp + (size_t)32 * NKV), O2);
    O3 = mfma16(ap, *(const bf16x8*)(vp + (size_t)48 * NKV), O3);
  }
#pragma unroll
  for (int r = 0; r < 4; ++r) lrow[r] = 1.0f / lrow[r];
  bf16* op = Ob + (size_t)(qRow0 + q0 + quad * 4) * DM + h * 64 + l15;
#pragma unroll
  for (int r = 0; r < 4; ++r) {
    float inv = lrow[r];
    op[(size_t)r * DM + 0]  = (bf16)(O0[r] * inv);
    op[(size_t)r * DM + 16] = (bf16)(O1[r] * inv);
    op[(size_t)r * DM + 32] = (bf16)(O2[r] * inv);
    op[(size_t)r * DM + 48] = (bf16)(O3[r] * inv);
  }
}

// ---------------- workspace layout (bytes) ----------------------------------
static const size_t OFF_COS = 0;           // 1280*32*4
static const size_t OFF_SIN = 163840;
static const size_t OFF_CAT = 327680;      // 1280*1024 f32
static const size_t OFF_XB  = 5570560;     // 1408*1024 bf16 (normed x + mem)
static const size_t OFF_QKV = 8454144;     // 2688*1024 f32 (Q/K only now)
static const size_t OFF_QB  = 25231360;    // 1280*1024 bf16
static const size_t OFF_KB  = 27852800;    // 1408*1024 bf16
static const size_t OFF_VT  = 30736384;    // 1024*1408 bf16
static const size_t OFF_OB  = 33619968;    // 1280*1024 bf16
static const size_t OFF_YB  = 36241408;    // 1280*1024 bf16
static const size_t OFF_WT  = 38862848;    // 18M elems bf16 transposed weights
static const size_t OFF_HB  = 97583104;    // 1280*2048 bf16
// total ~102.8 MB

extern "C" void kernel_launch(void* const* d_in, const int* in_sizes, int n_in,
                              void* d_out, int out_size, void* d_ws, size_t ws_size,
                              hipStream_t stream) {
  const int* ids = (const int*)d_in[0];
  const float* memory = (const float*)d_in[1];
  const float* beacon = (const float*)d_in[2];
  const float* forget = (const float*)d_in[3];
  const float* embed = (const float*)d_in[4];
  const float* ln1 = (const float*)d_in[5];
  const float* ln2 = (const float*)d_in[6];
  const float* Wq = (const float*)d_in[7];
  const float* Wk = (const float*)d_in[8];
  const float* Wv = (const float*)d_in[9];
  const float* Wo = (const float*)d_in[10];
  const float* mWk = (const float*)d_in[11];
  const float* mWv = (const float*)d_in[12];
  const float* bWq = (const float*)d_in[13];
  const float* bWk = (const float*)d_in[14];
  const float* bWv = (const float*)d_in[15];
  const float* fWq = (const float*)d_in[16];
  const float* fWk = (const float*)d_in[17];
  const float* fWv = (const float*)d_in[18];
  const float* Wg = (const float*)d_in[19];
  const float* Wu = (const float*)d_in[20];
  const float* Wd = (const float*)d_in[21];

  char* wsb = (char*)d_ws;
  float* cosT = (float*)(wsb + OFF_COS);
  float* sinT = (float*)(wsb + OFF_SIN);
  float* cat  = (float*)(wsb + OFF_CAT);
  bf16* xb    = (bf16*)(wsb + OFF_XB);
  float* qkv  = (float*)(wsb + OFF_QKV);
  bf16* Qb    = (bf16*)(wsb + OFF_QB);
  bf16* Kb    = (bf16*)(wsb + OFF_KB);
  bf16* Vt    = (bf16*)(wsb + OFF_VT);
  bf16* Ob    = (bf16*)(wsb + OFF_OB);
  bf16* yb    = (bf16*)(wsb + OFF_YB);
  bf16* wt    = (bf16*)(wsb + OFF_WT);
  bf16* Hb    = (bf16*)(wsb + OFF_HB);
  float* outp = (float*)d_out;

  // tiles are 64 (M) x 128 (N); kSplit multiplies tile count
  auto mkjob = [](const bf16* A, const bf16* B, const bf16* B2, void* C,
                  int K, int N, int ldC, int M, int mode, int kSplit, int& tiles) {
    GemmJob j; j.A = A; j.B = B; j.B2 = B2; j.C = C; j.K = K; j.N = N;
    j.ldC = ldC; j.tileStart = tiles; j.mode = mode; j.kSplit = kSplit;
    j.nMN = (M / 64) * (N / 128);
    tiles += j.nMN * kSplit;
    return j;
  };

  rope_table_kernel<<<1280, 32, 0, stream>>>(cosT, sinT);
  init_cat_kernel<<<1280, 256, 0, stream>>>(ids, embed, beacon, forget, cat);

  for (int l = 0; l < 8; ++l) {
    out_gate_kernel<<<128, 256, 0, stream>>>(cat, memory + (size_t)l * 131072,
                                             outp + (size_t)l * 131072);
    if (l == 7) break;  // layer 7's transform never affects outputs

    // ---- transpose+convert this layer's weights to bf16 (N x K) ----
    TransArgs ta; int tt = 0;
    const float* s12[12] = {Wq, Wk, Wv, Wo, mWk, mWv, bWq, bWk, bWv, fWq, fWk, fWv};
    for (int i = 0; i < 12; ++i) {
      ta.j[i].src = s12[i] + (size_t)l * 1048576;
      ta.j[i].dst = wt + (size_t)i * 1048576;
      ta.j[i].K = 1024; ta.j[i].N = 1024; ta.j[i].tileStart = tt; tt += 1024;
    }
    ta.j[12].src = Wg + (size_t)l * 2097152; ta.j[12].dst = wt + (size_t)12 * 1048576;
    ta.j[12].K = 1024; ta.j[12].N = 2048; ta.j[12].tileStart = tt; tt += 2048;
    ta.j[13].src = Wu + (size_t)l * 2097152; ta.j[13].dst = wt + (size_t)14 * 1048576;
    ta.j[13].K = 1024; ta.j[13].N = 2048; ta.j[13].tileStart = tt; tt += 2048;
    ta.j[14].src = Wd + (size_t)l * 2097152; ta.j[14].dst = wt + (size_t)16 * 1048576;
    ta.j[14].K = 2048; ta.j[14].N = 1024; ta.j[14].tileStart = tt; tt += 2048;
    ta.njobs = 15;
    trans_kernel<<<tt, 256, 0, stream>>>(ta);

    // ---- rmsnorm(cat, ln1) -> xb rows 0..1279; memory[l] -> rows 1280..1407
    rmsnorm_kernel<<<1408, 256, 0, stream>>>(cat, ln1 + (size_t)l * 1024, xb,
                                             memory + (size_t)l * 131072, 1280);

    // ---- projection GEMMs: Q/K -> qkv (f32); V -> Vt directly (bf16, T) ----
    auto xrow = [&](int r) { return xb + (size_t)r * DM; };
    auto crow = [&](int r) { return qkv + (size_t)r * DM; };
    auto wtm = [&](int i) { return wt + (size_t)i * 1048576; };
    GemmArgs ga; int tA = 0; int nj = 0;
    ga.j[nj++] = mkjob(xrow(0),    wtm(0),  nullptr, crow(0),    1024, 1024, 1024, 1024, 0, 1, tA); // Qh
    ga.j[nj++] = mkjob(xrow(1024), wtm(6),  nullptr, crow(1024), 1024, 1024, 1024, 128,  0, 1, tA); // bQ
    ga.j[nj++] = mkjob(xrow(1152), wtm(9),  nullptr, crow(1152), 1024, 1024, 1024, 128,  0, 1, tA); // fQ
    ga.j[nj++] = mkjob(xrow(1280), wtm(4),  nullptr, crow(1280), 1024, 1024, 1024, 128,  0, 1, tA); // mK
    ga.j[nj++] = mkjob(xrow(0),    wtm(1),  nullptr, crow(1408), 1024, 1024, 1024, 1024, 0, 1, tA); // Kh
    ga.j[nj++] = mkjob(xrow(1024), wtm(7),  nullptr, crow(2432), 1024, 1024, 1024, 128,  0, 1, tA); // bK
    ga.j[nj++] = mkjob(xrow(1152), wtm(10), nullptr, crow(2560), 1024, 1024, 1024, 128,  0, 1, tA); // fK
    // V^T = Wv_t @ x^T, written straight into Vt as bf16 (cols = key order)
    ga.j[nj++] = mkjob(wtm(5),  xrow(1280), nullptr, Vt + 0,    1024, 128,  1408, 1024, 2, 1, tA); // mV
    ga.j[nj++] = mkjob(wtm(2),  xrow(0),    nullptr, Vt + 128,  1024, 1024, 1408, 1024, 2, 1, tA); // Vh
    ga.j[nj++] = mkjob(wtm(8),  xrow(1024), nullptr, Vt + 1152, 1024, 128,  1408, 1024, 2, 1, tA); // bV
    ga.j[nj++] = mkjob(wtm(11), xrow(1152), nullptr, Vt + 1280, 1024, 128,  1408, 1024, 2, 1, tA); // fV
    ga.njobs = nj;
    gemm_kernel<<<tA, 256, 0, stream>>>(ga);

    // ---- rope Q/K -> bf16 ----
    rope_vt_kernel<<<2688, 256, 0, stream>>>(qkv, cosT, sinT, Qb, Kb);

    // ---- attention (hidden + beacon + forget) ----
    attn_kernel<<<1280, 64, 0, stream>>>(Qb, Kb, Vt, Ob);

    // ---- O @ Wo, atomic-add into cat (K split x2 for occupancy) ----
    GemmArgs gb; int tB = 0;
    gb.j[0] = mkjob(Ob, wtm(3), nullptr, cat, 1024, 1024, 1024, 1280, 4, 2, tB);
    gb.njobs = 1;
    gemm_kernel<<<tB, 256, 0, stream>>>(gb);

    // ---- rmsnorm2 -> yb ----
    rmsnorm_kernel<<<1280, 256, 0, stream>>>(cat, ln2 + (size_t)l * 1024, yb,
                                             nullptr, 1280);

    // ---- fused FFN: Hb = silu(y@Wg) * (y@Wu), bf16 ----
    GemmArgs gc; int tC = 0;
    gc.j[0] = mkjob(yb, wtm(12), wtm(14), Hb, 1024, 2048, 2048, 1280, 3, 1, tC);
    gc.njobs = 1;
    gemm_kernel<<<tC, 256, 0, stream>>>(gc);

    // ---- H @ Wd, atomic-add into cat (K split x2) ----
    GemmArgs gd; int tD = 0;
    gd.j[0] = mkjob(Hb, wtm(16), nullptr, cat, 2048, 1024, 1024, 1280, 4, 2, tD);
    gd.njobs = 1;
    gemm_kernel<<<tD, 256, 0, stream>>>(gd);
  }
}